// Round 14
// baseline (68.235 us; speedup 1.0000x reference)
//
#include <hip/hip_runtime.h>
#include <math.h>

typedef float f4v __attribute__((ext_vector_type(4)));
typedef float f2v __attribute__((ext_vector_type(2)));

// Problem constants (from reference setup_inputs)
constexpr int Bn = 4, Tn = 1000, Fn = 257, Cn = 6, Dn = 2048, On = 2;
constexpr int BTn = Bn * Tn;                      // 4000
constexpr double DEG2RAD = 0.017453292519943295;  // pi/180 in double

// Output segment offsets (in floats) within d_out
constexpr size_t OUT0_F = (size_t)BTn * Fn * Cn * 2;  // 12,336,000
constexpr size_t OUT1_F = (size_t)BTn * Fn * 2;       //  2,056,000

// Geometry
constexpr int DCH = 32;          // dirs per chunk
constexpr int NCH = Dn / DCH;    // 64 chunks
constexpr int FCH = 8;           // f per step (cd path)
constexpr int RWS = FCH * Cn;    // 48 rows per tile
constexpr int STEPS = 3;         // f-steps per cd block (double-buffered pipeline)
constexpr int FGRP = FCH * STEPS;             // 24 f per cd block
constexpr int YCDP = (Fn + FGRP - 1) / FGRP;  // 11
constexpr int FCB = 24;          // f per chunk (b path)
constexpr int RWB = FCB * On;    // 48 rows
constexpr int YB  = (Fn + FCB - 1) / FCB;     // 11
constexpr int DPAD = 34;         // f2v per row (32 + 2 pad; 272B row, 16B-aligned)
constexpr int TILE = RWS * DPAD; // 1632 f2v per tile
constexpr int NT = 512;          // threads per fuse block (8 waves)

// Workspace layout (bytes)
constexpr size_t TAB_BYTES  = (size_t)4 * Dn * sizeof(double);   // 65,536
constexpr size_t BTT_PAD    = 131072;
constexpr size_t IND_BYTES  = 16384;
constexpr size_t BOFF_BYTES = 4096;
constexpr size_t BENT_BYTES = 16384;
constexpr size_t WS_NEEDED  = TAB_BYTES + BTT_PAD + IND_BYTES + BOFF_BYTES + BENT_BYTES;

// ---------------------------------------------------------------------------
// K0: trig tables in double (verified bit-exact vs np in R4/R7).
// ---------------------------------------------------------------------------
__global__ __launch_bounds__(256) void build_tables(const float2* __restrict__ dirs,
                                                    const float* __restrict__ tdoa,
                                                    double* __restrict__ tab,
                                                    double* __restrict__ bttab) {
    int id = blockIdx.x * 256 + threadIdx.x;
    if (id < Dn) {
        float2 dr = dirs[id];
        double d0 = (double)dr.x, d1 = (double)dr.y;
        tab[0 * Dn + id] = cos(d0);
        tab[1 * Dn + id] = sin(d0);
        tab[2 * Dn + id] = cos(d1);
        tab[3 * Dn + id] = sin(d1);
    } else if (id < Dn + BTn) {
        int bt = id - Dn;
        double t0 = DEG2RAD * (double)tdoa[bt * 2 + 0];
        double t1 = DEG2RAD * (double)tdoa[bt * 2 + 1];
        bttab[bt * 4 + 0] = cos(t0);
        bttab[bt * 4 + 1] = sin(t0);
        bttab[bt * 4 + 2] = cos(t1);
        bttab[bt * 4 + 3] = sin(t1);
    }
}

// ---------------------------------------------------------------------------
// K1: argmin over direction codebook (verified passing R7-R13, unchanged).
// ---------------------------------------------------------------------------
__global__ __launch_bounds__(256) void argmin_lds(const double* __restrict__ bttab,
                                                  const double* __restrict__ tab,
                                                  int* __restrict__ ind) {
    __shared__ double s_cd0[Dn];
    __shared__ double s_sd0[Dn];
    __shared__ double s_cd1[Dn];
    __shared__ double s_sd1[Dn];
    const int t = threadIdx.x;
    #pragma unroll
    for (int k = 0; k < Dn / 256; ++k) {
        int d = t + 256 * k;
        s_cd0[d] = tab[0 * Dn + d];
        s_sd0[d] = tab[1 * Dn + d];
        s_cd1[d] = tab[2 * Dn + d];
        s_sd1[d] = tab[3 * Dn + d];
    }
    __syncthreads();
    const int w = t >> 6, lane = t & 63;
    #pragma unroll
    for (int s = 0; s < 4; ++s) {
        const int bt = blockIdx.x * 16 + w * 4 + s;
        double ct0 = bttab[bt * 4 + 0], st0 = bttab[bt * 4 + 1];
        double ct1 = bttab[bt * 4 + 2], st1 = bttab[bt * 4 + 3];
        double best = 1e300;
        int bidx = 0;
        for (int i = 0; i < Dn / 256; ++i) {
            const int d0 = lane + 256 * i;
            double a[4];
            #pragma unroll
            for (int k = 0; k < 4; ++k) {
                int d = d0 + 64 * k;
                double u  = ct1 * s_cd1[d];
                double m1 = 1.0 - (u + st1 * s_sd1[d]);
                double m0 = 1.0 - (ct0 * s_cd0[d] + st0 * s_sd0[d]);
                a[k] = m1 + u * m0;
            }
            #pragma unroll
            for (int k = 0; k < 4; ++k) {
                int d = d0 + 64 * k;
                if (a[k] < best) { best = a[k]; bidx = d; }
            }
        }
        #pragma unroll
        for (int off = 32; off > 0; off >>= 1) {
            double ov = __shfl_down(best, off);
            int oi = __shfl_down(bidx, off);
            if (ov < best || (ov == best && oi < bidx)) { best = ov; bidx = oi; }
        }
        if (lane == 0) ind[bt] = bidx;
    }
}

// ---------------------------------------------------------------------------
// K2: bucket bts by 32-wide d-chunk (verified R10-R13, unchanged).
// ---------------------------------------------------------------------------
__global__ __launch_bounds__(256) void bucket_bts(const int* __restrict__ ind,
                                                  int* __restrict__ boff,
                                                  int* __restrict__ bent) {
    __shared__ int cnts[NCH];
    __shared__ int curs[NCH];
    const int t = threadIdx.x;
    if (t < NCH) cnts[t] = 0;
    __syncthreads();
    #pragma unroll
    for (int k = 0; k < (BTn + 255) / 256; ++k) {
        int bt = k * 256 + t;
        if (bt < BTn) atomicAdd(&cnts[ind[bt] >> 5], 1);
    }
    __syncthreads();
    if (t == 0) {
        int acc = 0;
        for (int i = 0; i < NCH; ++i) { curs[i] = acc; boff[i] = acc; acc += cnts[i]; }
        boff[NCH] = acc;
    }
    __syncthreads();
    #pragma unroll
    for (int k = 0; k < (BTn + 255) / 256; ++k) {
        int bt = k * 256 + t;
        if (bt < BTn) {
            int d = ind[bt];
            int p = atomicAdd(&curs[d >> 5], 1);
            bent[p] = (bt << 5) | (d & 31);
        }
    }
}

// ---------------------------------------------------------------------------
// K3: fused gather-multiply. cd path = 3-step double-buffered pipeline:
// weights for step s+1 issue before step s's item loop (latency under compute),
// ds_write after, one barrier per step. b path = single-shot panel copy.
// LDS 52,224B. Grid (64, 22), 512 threads.
// ---------------------------------------------------------------------------
__global__ __launch_bounds__(NT) void fuse_all(
    const float* __restrict__ Xr, const float* __restrict__ Xi,
    const int* __restrict__ boff, const int* __restrict__ bent,
    const float* __restrict__ wcr, const float* __restrict__ wci,
    const float* __restrict__ wdr, const float* __restrict__ wdi,
    const float* __restrict__ wbr, const float* __restrict__ wbi,
    float* __restrict__ out0, float* __restrict__ out1, float* __restrict__ out2) {
    __shared__ __align__(16) f2v buf[2][2 * TILE];   // 52,224 B
    const int bx = blockIdx.x;
    const int d0 = bx * DCH;
    const int t = threadIdx.x;
    const int off = boff[bx];
    const int cnt = boff[bx + 1] - off;

    if (blockIdx.y < YCDP) {
        // ------------------------- cd path (3-step pipeline) -------------------------
        const int fbase = blockIdx.y * FGRP;
        const int items = cnt * FCH;

        // Staging item 0: idx = t (<768 always); item 1: idx = 512+t (t<256).
        // pair = idx>=384 (0:wc, 1:wd); k = idx-pair*384; r=k>>3; q4=k&7.
        auto wsrc = [&](int pair, int re, int r, int q4, int f0) -> const f4v* {
            int fi = r / Cn, c = r - fi * Cn;
            int f = f0 + fi;
            if (f >= Fn) return (const f4v*)nullptr;
            const float* p = pair ? (re ? wdr : wdi) : (re ? wcr : wci);
            return (const f4v*)(p + (size_t)(c * Fn + f) * Dn + d0 + 4 * q4);
        };
        const int i0 = t;
        const int p0 = (i0 >= 384) ? 1 : 0;
        const int k0 = i0 - p0 * 384, r0 = k0 >> 3, q0 = k0 & 7;
        const int i1 = NT + t;
        const bool h1 = (i1 < 768);
        const int p1 = 1;                     // 512+t >= 384 always
        const int k1 = i1 - 384, r1 = k1 >> 3, q1 = k1 & 7;

        // ---- prologue: weights step0 + X batch0 step0 ----
        f4v w0r = {0,0,0,0}, w0i = {0,0,0,0}, w1r = {0,0,0,0}, w1i = {0,0,0,0};
        {
            const f4v* a = wsrc(p0, 1, r0, q0, fbase);
            const f4v* b = wsrc(p0, 0, r0, q0, fbase);
            if (a) { w0r = *a; w0i = *b; }
            if (h1) {
                const f4v* c2 = wsrc(p1, 1, r1, q1, fbase);
                const f4v* d2 = wsrc(p1, 0, r1, q1, fbase);
                if (c2) { w1r = *c2; w1i = *d2; }
            }
        }
        bool vA = false; int btA = 0, fA = 0, dlA = 0, rbA = 0;
        f2v xrA0 = {0,0}, xrA1 = {0,0}, xrA2 = {0,0};
        f2v xiA0 = {0,0}, xiA1 = {0,0}, xiA2 = {0,0};
        if (t < items) {
            int e = bent[off + (t >> 3)];
            int fi = t & 7, f = fbase + fi;
            if (f < Fn) {
                vA = true; btA = e >> 5; fA = f; dlA = e & 31; rbA = fi * Cn;
                size_t xb = ((size_t)btA * Fn + f) * Cn;
                const f2v* xr2 = (const f2v*)(Xr + xb);
                const f2v* xi2 = (const f2v*)(Xi + xb);
                xrA0 = xr2[0]; xrA1 = xr2[1]; xrA2 = xr2[2];
                xiA0 = xi2[0]; xiA1 = xi2[1]; xiA2 = xi2[2];
            }
        }
        // write step0 tiles into buf[0]
        {
            f4v* row0 = (f4v*)&buf[0][p0 * TILE + r0 * DPAD];
            f4v lo0 = {w0r[0], w0i[0], w0r[1], w0i[1]};
            f4v hi0 = {w0r[2], w0i[2], w0r[3], w0i[3]};
            row0[2 * q0] = lo0; row0[2 * q0 + 1] = hi0;
            if (h1) {
                f4v* row1 = (f4v*)&buf[0][p1 * TILE + r1 * DPAD];
                f4v lo1 = {w1r[0], w1i[0], w1r[1], w1i[1]};
                f4v hi1 = {w1r[2], w1i[2], w1r[3], w1i[3]};
                row1[2 * q1] = lo1; row1[2 * q1 + 1] = hi1;
            }
        }
        __syncthreads();

        for (int s = 0; s < STEPS; ++s) {
            const int f0 = fbase + s * FCH;
            const f2v* tc = &buf[s & 1][0];
            const f2v* td = &buf[s & 1][TILE];
            const bool more = (s + 1 < STEPS);

            // ---- issue next step's weight loads (hide under item loop) ----
            f4v nw0r = {0,0,0,0}, nw0i = {0,0,0,0}, nw1r = {0,0,0,0}, nw1i = {0,0,0,0};
            if (more) {
                const f4v* a = wsrc(p0, 1, r0, q0, f0 + FCH);
                const f4v* b = wsrc(p0, 0, r0, q0, f0 + FCH);
                if (a) { nw0r = *a; nw0i = *b; }
                if (h1) {
                    const f4v* c2 = wsrc(p1, 1, r1, q1, f0 + FCH);
                    const f4v* d2 = wsrc(p1, 0, r1, q1, f0 + FCH);
                    if (c2) { nw1r = *c2; nw1i = *d2; }
                }
            }

            // ---- item loop (in-step batch-ahead X prefetch) ----
            for (int base = 0; base < items; base += NT) {
                bool vB = false; int btB = 0, fB = 0, dlB = 0, rbB = 0;
                f2v xrB0 = {0,0}, xrB1 = {0,0}, xrB2 = {0,0};
                f2v xiB0 = {0,0}, xiB1 = {0,0}, xiB2 = {0,0};
                int itn = base + NT + t;
                if (itn < items) {
                    int e = bent[off + (itn >> 3)];
                    int fi = itn & 7, f = f0 + fi;
                    if (f < Fn) {
                        vB = true; btB = e >> 5; fB = f; dlB = e & 31; rbB = fi * Cn;
                        size_t xb = ((size_t)btB * Fn + f) * Cn;
                        const f2v* xr2 = (const f2v*)(Xr + xb);
                        const f2v* xi2 = (const f2v*)(Xi + xb);
                        xrB0 = xr2[0]; xrB1 = xr2[1]; xrB2 = xr2[2];
                        xiB0 = xi2[0]; xiB1 = xi2[1]; xiB2 = xi2[2];
                    }
                }
                if (vA) {
                    float xr[Cn] = {xrA0[0], xrA0[1], xrA1[0], xrA1[1], xrA2[0], xrA2[1]};
                    float xi[Cn] = {xiA0[0], xiA0[1], xiA1[0], xiA1[1], xiA2[0], xiA2[1]};
                    float o0[Cn * 2];
                    float accr = 0.f, acci = 0.f;
                    #pragma unroll
                    for (int c = 0; c < Cn; ++c) {
                        f2v wcv = tc[(rbA + c) * DPAD + dlA];
                        f2v wdv = td[(rbA + c) * DPAD + dlA];
                        o0[2 * c]     = wdv[0] * xr[c] - wdv[1] * xi[c];
                        o0[2 * c + 1] = wdv[0] * xi[c] + wdv[1] * xr[c];
                        accr += wcv[0] * xr[c] - wcv[1] * xi[c];
                        acci += wcv[0] * xi[c] + wcv[1] * xr[c];
                    }
                    size_t xb = ((size_t)btA * Fn + fA) * Cn;
                    f4v* ob = (f4v*)(out0 + xb * 2);
                    f4v pp0 = {o0[0], o0[1], o0[2], o0[3]};
                    f4v pp1 = {o0[4], o0[5], o0[6], o0[7]};
                    f4v pp2 = {o0[8], o0[9], o0[10], o0[11]};
                    ob[0] = pp0; ob[1] = pp1; ob[2] = pp2;
                    f2v o1 = {accr, acci};
                    ((f2v*)out1)[(size_t)btA * Fn + fA] = o1;
                }
                vA = vB; btA = btB; fA = fB; dlA = dlB; rbA = rbB;
                xrA0 = xrB0; xrA1 = xrB1; xrA2 = xrB2;
                xiA0 = xiB0; xiA1 = xiB1; xiA2 = xiB2;
            }

            if (more) {
                // ---- prefetch X batch0 of next step (lands across barrier) ----
                vA = false;
                if (t < items) {
                    int e = bent[off + (t >> 3)];
                    int fi = t & 7, f = f0 + FCH + fi;
                    if (f < Fn) {
                        vA = true; btA = e >> 5; fA = f; dlA = e & 31; rbA = fi * Cn;
                        size_t xb = ((size_t)btA * Fn + f) * Cn;
                        const f2v* xr2 = (const f2v*)(Xr + xb);
                        const f2v* xi2 = (const f2v*)(Xi + xb);
                        xrA0 = xr2[0]; xrA1 = xr2[1]; xrA2 = xr2[2];
                        xiA0 = xi2[0]; xiA1 = xi2[1]; xiA2 = xi2[2];
                    }
                }
                // ---- write next step's tiles into the other buffer ----
                f4v* row0 = (f4v*)&buf[(s + 1) & 1][p0 * TILE + r0 * DPAD];
                f4v lo0 = {nw0r[0], nw0i[0], nw0r[1], nw0i[1]};
                f4v hi0 = {nw0r[2], nw0i[2], nw0r[3], nw0i[3]};
                row0[2 * q0] = lo0; row0[2 * q0 + 1] = hi0;
                if (h1) {
                    f4v* row1 = (f4v*)&buf[(s + 1) & 1][p1 * TILE + r1 * DPAD];
                    f4v lo1 = {nw1r[0], nw1i[0], nw1r[1], nw1i[1]};
                    f4v hi1 = {nw1r[2], nw1i[2], nw1r[3], nw1i[3]};
                    row1[2 * q1] = lo1; row1[2 * q1 + 1] = hi1;
                }
                __syncthreads();
            }
        }
    } else {
        // ------------------------- b path (single-shot) -------------------------
        f2v* tb = &buf[0][0];
        const int f0 = (blockIdx.y - YCDP) * FCB;
        {   // 48 rows x 8 f4 = 384 items
            int idx = t;
            if (idx < RWB * 8) {
                int r = idx >> 3, q4 = idx & 7;
                int fi = r >> 1, o = r & 1;
                int f = f0 + fi;
                if (f < Fn) {
                    size_t s = (size_t)(o * Fn + f) * Dn + d0 + 4 * q4;
                    f4v vr = *(const f4v*)(wbr + s);
                    f4v vi = *(const f4v*)(wbi + s);
                    f4v* trow = (f4v*)&tb[r * DPAD];
                    f4v lo = {vr[0], vi[0], vr[1], vi[1]};
                    f4v hi = {vr[2], vi[2], vr[3], vi[3]};
                    trow[2 * q4]     = lo;
                    trow[2 * q4 + 1] = hi;
                }
            }
        }
        __syncthreads();
        const int items = cnt * FCB;
        for (int base = 0; base < items; base += NT) {
            int it = base + t;
            if (it < items) {
                int m = it / FCB, fi = it - m * FCB;
                int e = bent[off + m];
                int bt = e >> 5, dl = e & 31;
                int f = f0 + fi;
                if (f < Fn) {
                    f2v a = tb[(fi * 2) * DPAD + dl];
                    f2v b = tb[(fi * 2 + 1) * DPAD + dl];
                    f4v o2 = {a[0], a[1], b[0], b[1]};
                    ((f4v*)out2)[(size_t)bt * Fn + f] = o2;
                }
            }
        }
    }
}

// Fallback (no workspace): direct strided gather, per-block argmin
__global__ __launch_bounds__(256) void main_direct(
    const float* __restrict__ Xr, const float* __restrict__ Xi,
    const float* __restrict__ tdoa, const float2* __restrict__ dirs,
    const float* __restrict__ wcr, const float* __restrict__ wci,
    const float* __restrict__ wdr, const float* __restrict__ wdi,
    const float* __restrict__ wbr, const float* __restrict__ wbi,
    float2* __restrict__ out0, float2* __restrict__ out1, float2* __restrict__ out2) {
    const int bt = blockIdx.x;
    const int tid = threadIdx.x;
    __shared__ double sv[256];
    __shared__ int si[256];

    double t0 = DEG2RAD * (double)tdoa[bt * 2 + 0];
    double t1 = DEG2RAD * (double)tdoa[bt * 2 + 1];
    double ct1 = cos(t1);
    double best = 1e300;
    int bidx = 0;
    for (int d = tid; d < Dn; d += 256) {
        float2 dr = dirs[d];
        double s1 = sin(0.5 * (t1 - (double)dr.y));
        double s2 = sin(0.5 * (t0 - (double)dr.x));
        double a = s1 * s1 + ct1 * cos((double)dr.y) * (s2 * s2);
        if (a < best) { best = a; bidx = d; }
    }
    sv[tid] = best; si[tid] = bidx;
    __syncthreads();
    for (int s = 128; s > 0; s >>= 1) {
        if (tid < s) {
            double v = sv[tid + s]; int j = si[tid + s];
            if (v < sv[tid] || (v == sv[tid] && j < si[tid])) { sv[tid] = v; si[tid] = j; }
        }
        __syncthreads();
    }
    const int dsel = si[0];
    const size_t base = (size_t)bt * Fn * Cn;

    for (int f = tid; f < Fn; f += 256) {
        const int fc = f * Cn;
        float accr = 0.f, acci = 0.f;
        #pragma unroll
        for (int c = 0; c < Cn; ++c) {
            float xr = Xr[base + fc + c], xi = Xi[base + fc + c];
            size_t wo = (size_t)(c * Fn + f) * Dn + dsel;
            float a_ = wdr[wo], b_ = wdi[wo];
            out0[base + fc + c] = make_float2(a_ * xr - b_ * xi, a_ * xi + b_ * xr);
            float p = wcr[wo], q = wci[wo];
            accr += p * xr - q * xi;
            acci += p * xi + q * xr;
        }
        out1[(size_t)bt * Fn + f] = make_float2(accr, acci);
        #pragma unroll
        for (int o = 0; o < On; ++o) {
            size_t wo = (size_t)(o * Fn + f) * Dn + dsel;
            out2[((size_t)bt * Fn + f) * On + o] = make_float2(wbr[wo], wbi[wo]);
        }
    }
}

extern "C" void kernel_launch(void* const* d_in, const int* in_sizes, int n_in,
                              void* d_out, int out_size, void* d_ws, size_t ws_size,
                              hipStream_t stream) {
    const float* Xr   = (const float*)d_in[0];
    const float* Xi   = (const float*)d_in[1];
    const float* tdoa = (const float*)d_in[2];
    const float2* dirs = (const float2*)d_in[3];
    const float* wcr = (const float*)d_in[4];
    const float* wci = (const float*)d_in[5];
    const float* wdr = (const float*)d_in[6];
    const float* wdi = (const float*)d_in[7];
    const float* wbr = (const float*)d_in[8];
    const float* wbi = (const float*)d_in[9];

    float* out = (float*)d_out;

    if (ws_size >= WS_NEEDED) {
        char* ws = (char*)d_ws;
        double* tab   = (double*)ws;
        double* bttab = (double*)(ws + TAB_BYTES);
        int* ind  = (int*)(ws + TAB_BYTES + BTT_PAD);
        int* boff = (int*)(ws + TAB_BYTES + BTT_PAD + IND_BYTES);
        int* bent = (int*)(ws + TAB_BYTES + BTT_PAD + IND_BYTES + BOFF_BYTES);

        build_tables<<<(Dn + BTn + 255) / 256, 256, 0, stream>>>(dirs, tdoa, tab, bttab);
        argmin_lds<<<BTn / 16, 256, 0, stream>>>(bttab, tab, ind);
        bucket_bts<<<1, 256, 0, stream>>>(ind, boff, bent);
        dim3 g(NCH, YCDP + YB);   // 64 x 22
        fuse_all<<<g, NT, 0, stream>>>(Xr, Xi, boff, bent,
                                       wcr, wci, wdr, wdi, wbr, wbi,
                                       out, out + OUT0_F, out + OUT0_F + OUT1_F);
    } else {
        main_direct<<<BTn, 256, 0, stream>>>(Xr, Xi, tdoa, dirs,
                                             wcr, wci, wdr, wdi, wbr, wbi,
                                             (float2*)out,
                                             (float2*)(out + OUT0_F),
                                             (float2*)(out + OUT0_F + OUT1_F));
    }
}

// Round 15
// 60.857 us; speedup vs baseline: 1.1212x; 1.1212x over previous
//
#include <hip/hip_runtime.h>
#include <math.h>

typedef float f4v __attribute__((ext_vector_type(4)));
typedef float f2v __attribute__((ext_vector_type(2)));

// Problem constants (from reference setup_inputs)
constexpr int Bn = 4, Tn = 1000, Fn = 257, Cn = 6, Dn = 2048, On = 2;
constexpr int BTn = Bn * Tn;                      // 4000
constexpr double DEG2RAD = 0.017453292519943295;  // pi/180 in double

// Output segment offsets (in floats) within d_out
constexpr size_t OUT0_F = (size_t)BTn * Fn * Cn * 2;  // 12,336,000
constexpr size_t OUT1_F = (size_t)BTn * Fn * 2;       //  2,056,000

// d-chunking for the fused gather kernel (R13 geometry: DCH=32, NT=512)
constexpr int DCH = 32;          // dirs per chunk
constexpr int NCH = Dn / DCH;    // 64 chunks
constexpr int FCH = 8;           // f per chunk (cd path)
constexpr int RWS = FCH * Cn;    // 48 rows
constexpr int FCB = 24;          // f per chunk (b path)
constexpr int RWB = FCB * On;    // 48 rows
constexpr int YCD = (Fn + FCH - 1) / FCH;  // 33
constexpr int YB  = (Fn + FCB - 1) / FCB;  // 11
constexpr int YTOT = YCD + YB;             // 44 y-units per d-chunk
constexpr int DPAD = 34;         // f2v per row (32 + 2 pad; 272B row, 16B-aligned)
constexpr int NT = 512;          // threads per fuse block (8 waves)
constexpr int NXCD = 8;
constexpr int GRP = NXCD * YTOT; // 352 blocks per d-chunk-octet

// Workspace layout (bytes)
constexpr size_t TAB_BYTES  = (size_t)4 * Dn * sizeof(double);   // 65,536
constexpr size_t BTT_PAD    = 131072;                            // 4000*4 doubles padded
constexpr size_t IND_BYTES  = 16384;                             // 4000 ints padded
constexpr size_t BOFF_BYTES = 4096;                              // 65 ints padded
constexpr size_t BENT_BYTES = 16384;                             // 4000 ints padded
constexpr size_t WS_NEEDED  = TAB_BYTES + BTT_PAD + IND_BYTES + BOFF_BYTES + BENT_BYTES;

// ---------------------------------------------------------------------------
// K0: trig tables in double (verified bit-exact vs np in R4/R7).
// ---------------------------------------------------------------------------
__global__ __launch_bounds__(256) void build_tables(const float2* __restrict__ dirs,
                                                    const float* __restrict__ tdoa,
                                                    double* __restrict__ tab,
                                                    double* __restrict__ bttab) {
    int id = blockIdx.x * 256 + threadIdx.x;
    if (id < Dn) {
        float2 dr = dirs[id];
        double d0 = (double)dr.x, d1 = (double)dr.y;
        tab[0 * Dn + id] = cos(d0);
        tab[1 * Dn + id] = sin(d0);
        tab[2 * Dn + id] = cos(d1);
        tab[3 * Dn + id] = sin(d1);
    } else if (id < Dn + BTn) {
        int bt = id - Dn;
        double t0 = DEG2RAD * (double)tdoa[bt * 2 + 0];
        double t1 = DEG2RAD * (double)tdoa[bt * 2 + 1];
        bttab[bt * 4 + 0] = cos(t0);
        bttab[bt * 4 + 1] = sin(t0);
        bttab[bt * 4 + 2] = cos(t1);
        bttab[bt * 4 + 3] = sin(t1);
    }
}

// ---------------------------------------------------------------------------
// K1: argmin over direction codebook (verified passing R7-R14, unchanged).
// ---------------------------------------------------------------------------
__global__ __launch_bounds__(256) void argmin_lds(const double* __restrict__ bttab,
                                                  const double* __restrict__ tab,
                                                  int* __restrict__ ind) {
    __shared__ double s_cd0[Dn];
    __shared__ double s_sd0[Dn];
    __shared__ double s_cd1[Dn];
    __shared__ double s_sd1[Dn];
    const int t = threadIdx.x;
    #pragma unroll
    for (int k = 0; k < Dn / 256; ++k) {
        int d = t + 256 * k;
        s_cd0[d] = tab[0 * Dn + d];
        s_sd0[d] = tab[1 * Dn + d];
        s_cd1[d] = tab[2 * Dn + d];
        s_sd1[d] = tab[3 * Dn + d];
    }
    __syncthreads();
    const int w = t >> 6, lane = t & 63;
    #pragma unroll
    for (int s = 0; s < 4; ++s) {
        const int bt = blockIdx.x * 16 + w * 4 + s;
        double ct0 = bttab[bt * 4 + 0], st0 = bttab[bt * 4 + 1];
        double ct1 = bttab[bt * 4 + 2], st1 = bttab[bt * 4 + 3];
        double best = 1e300;
        int bidx = 0;
        for (int i = 0; i < Dn / 256; ++i) {
            const int d0 = lane + 256 * i;
            double a[4];
            #pragma unroll
            for (int k = 0; k < 4; ++k) {
                int d = d0 + 64 * k;
                double u  = ct1 * s_cd1[d];
                double m1 = 1.0 - (u + st1 * s_sd1[d]);
                double m0 = 1.0 - (ct0 * s_cd0[d] + st0 * s_sd0[d]);
                a[k] = m1 + u * m0;
            }
            #pragma unroll
            for (int k = 0; k < 4; ++k) {
                int d = d0 + 64 * k;
                if (a[k] < best) { best = a[k]; bidx = d; }
            }
        }
        #pragma unroll
        for (int off = 32; off > 0; off >>= 1) {
            double ov = __shfl_down(best, off);
            int oi = __shfl_down(bidx, off);
            if (ov < best || (ov == best && oi < bidx)) { best = ov; bidx = oi; }
        }
        if (lane == 0) ind[bt] = bidx;
    }
}

// ---------------------------------------------------------------------------
// K2: bucket bts by 32-wide d-chunk (verified R10-R14, unchanged).
// ---------------------------------------------------------------------------
__global__ __launch_bounds__(256) void bucket_bts(const int* __restrict__ ind,
                                                  int* __restrict__ boff,
                                                  int* __restrict__ bent) {
    __shared__ int cnts[NCH];
    __shared__ int curs[NCH];
    const int t = threadIdx.x;
    if (t < NCH) cnts[t] = 0;
    __syncthreads();
    #pragma unroll
    for (int k = 0; k < (BTn + 255) / 256; ++k) {
        int bt = k * 256 + t;
        if (bt < BTn) atomicAdd(&cnts[ind[bt] >> 5], 1);
    }
    __syncthreads();
    if (t == 0) {
        int acc = 0;
        for (int i = 0; i < NCH; ++i) { curs[i] = acc; boff[i] = acc; acc += cnts[i]; }
        boff[NCH] = acc;
    }
    __syncthreads();
    #pragma unroll
    for (int k = 0; k < (BTn + 255) / 256; ++k) {
        int bt = k * 256 + t;
        if (bt < BTn) {
            int d = ind[bt];
            int p = atomicAdd(&curs[d >> 5], 1);
            bent[p] = (bt << 5) | (d & 31);
        }
    }
}

// ---------------------------------------------------------------------------
// K3: fused gather-multiply (R13 structure) + XCD-locality block remap (T1).
// Linear block id v -> (dch, yu) such that XCD(v)=v%8 is constant for all 44
// y-units of a d-chunk: dch = (v/GRP)*8 + v%8, yu = (v%GRP)/8. All blocks
// sharing a weight tile then hit the SAME XCD L2 -> lines fetched once.
// ---------------------------------------------------------------------------
__global__ __launch_bounds__(NT) void fuse_all(
    const float* __restrict__ Xr, const float* __restrict__ Xi,
    const int* __restrict__ boff, const int* __restrict__ bent,
    const float* __restrict__ wcr, const float* __restrict__ wci,
    const float* __restrict__ wdr, const float* __restrict__ wdi,
    const float* __restrict__ wbr, const float* __restrict__ wbi,
    float* __restrict__ out0, float* __restrict__ out1, float* __restrict__ out2) {
    __shared__ __align__(16) char smem[2 * RWS * DPAD * sizeof(f2v)];
    const int v = blockIdx.x;
    const int q = v / GRP, r = v % GRP;
    const int bx = q * NXCD + (r % NXCD);   // d-chunk (pinned to XCD r%8)
    const int yu = r / NXCD;                // y-unit 0..43
    const int d0 = bx * DCH;
    const int t = threadIdx.x;
    const int off = boff[bx];
    const int cnt = boff[bx + 1] - off;

    if (yu < YCD) {
        // ------------------------- cd path -------------------------
        f2v (*tc)[DPAD] = (f2v(*)[DPAD])smem;
        f2v (*td)[DPAD] = (f2v(*)[DPAD])(smem + sizeof(f2v) * RWS * DPAD);
        const int f0 = yu * FCH;
        const int items = cnt * FCH;

        // ---- prefetch batch-0 X into registers (independent of staging) ----
        bool vA = false; int btA = 0, fA = 0, dlA = 0, rbA = 0;
        f2v xrA0 = {0,0}, xrA1 = {0,0}, xrA2 = {0,0};
        f2v xiA0 = {0,0}, xiA1 = {0,0}, xiA2 = {0,0};
        if (t < items) {
            int e = bent[off + (t >> 3)];
            int fi = t & 7, f = f0 + fi;
            if (f < Fn) {
                vA = true; btA = e >> 5; fA = f; dlA = e & 31; rbA = fi * Cn;
                size_t xb = ((size_t)btA * Fn + f) * Cn;
                const f2v* xr2 = (const f2v*)(Xr + xb);
                const f2v* xi2 = (const f2v*)(Xi + xb);
                xrA0 = xr2[0]; xrA1 = xr2[1]; xrA2 = xr2[2];
                xiA0 = xi2[0]; xiA1 = xi2[1]; xiA2 = xi2[2];
            }
        }
        // ---- stage wc & wd tiles: 2 pairs x 48 rows x 8 f4 = 768 items ----
        #pragma unroll
        for (int j = 0; j < 2; ++j) {
            int idx = j * NT + t;
            if (idx < 768) {
                const int pair = (idx >= 384) ? 1 : 0;
                int k = idx - pair * 384;
                int rr = k >> 3, q4 = k & 7;
                int fi = rr / Cn, c = rr - fi * Cn;
                int f = f0 + fi;
                if (f < Fn) {
                    size_t s = (size_t)(c * Fn + f) * Dn + d0 + 4 * q4;
                    f4v vr = *(const f4v*)((pair ? wdr : wcr) + s);
                    f4v vi = *(const f4v*)((pair ? wdi : wci) + s);
                    f4v* trow = (f4v*)&(pair ? td : tc)[rr][0];
                    f4v lo = {vr[0], vi[0], vr[1], vi[1]};
                    f4v hi = {vr[2], vi[2], vr[3], vi[3]};
                    trow[2 * q4]     = lo;
                    trow[2 * q4 + 1] = hi;
                }
            }
        }
        __syncthreads();

        // ---- item loop (usually a single batch) with next-batch prefetch ----
        for (int base = 0; base < items; base += NT) {
            bool vB = false; int btB = 0, fB = 0, dlB = 0, rbB = 0;
            f2v xrB0 = {0,0}, xrB1 = {0,0}, xrB2 = {0,0};
            f2v xiB0 = {0,0}, xiB1 = {0,0}, xiB2 = {0,0};
            int itn = base + NT + t;
            if (itn < items) {
                int e = bent[off + (itn >> 3)];
                int fi = itn & 7, f = f0 + fi;
                if (f < Fn) {
                    vB = true; btB = e >> 5; fB = f; dlB = e & 31; rbB = fi * Cn;
                    size_t xb = ((size_t)btB * Fn + f) * Cn;
                    const f2v* xr2 = (const f2v*)(Xr + xb);
                    const f2v* xi2 = (const f2v*)(Xi + xb);
                    xrB0 = xr2[0]; xrB1 = xr2[1]; xrB2 = xr2[2];
                    xiB0 = xi2[0]; xiB1 = xi2[1]; xiB2 = xi2[2];
                }
            }
            if (vA) {
                float xr[Cn] = {xrA0[0], xrA0[1], xrA1[0], xrA1[1], xrA2[0], xrA2[1]};
                float xi[Cn] = {xiA0[0], xiA0[1], xiA1[0], xiA1[1], xiA2[0], xiA2[1]};
                float o0[Cn * 2];
                float accr = 0.f, acci = 0.f;
                #pragma unroll
                for (int c = 0; c < Cn; ++c) {
                    f2v wcv = tc[rbA + c][dlA];
                    f2v wdv = td[rbA + c][dlA];
                    o0[2 * c]     = wdv[0] * xr[c] - wdv[1] * xi[c];
                    o0[2 * c + 1] = wdv[0] * xi[c] + wdv[1] * xr[c];
                    accr += wcv[0] * xr[c] - wcv[1] * xi[c];
                    acci += wcv[0] * xi[c] + wcv[1] * xr[c];
                }
                size_t xb = ((size_t)btA * Fn + fA) * Cn;
                f4v* ob = (f4v*)(out0 + xb * 2);          // 48B-multiple -> 16B aligned
                f4v p0 = {o0[0], o0[1], o0[2], o0[3]};
                f4v p1 = {o0[4], o0[5], o0[6], o0[7]};
                f4v p2 = {o0[8], o0[9], o0[10], o0[11]};
                ob[0] = p0; ob[1] = p1; ob[2] = p2;       // cached: L2 merges lines
                f2v o1 = {accr, acci};
                ((f2v*)out1)[(size_t)btA * Fn + fA] = o1;
            }
            vA = vB; btA = btB; fA = fB; dlA = dlB; rbA = rbB;
            xrA0 = xrB0; xrA1 = xrB1; xrA2 = xrB2;
            xiA0 = xiB0; xiA1 = xiB1; xiA2 = xiB2;
        }
    } else {
        // ------------------------- b path -------------------------
        f2v (*tb)[DPAD] = (f2v(*)[DPAD])smem;
        const int f0 = (yu - YCD) * FCB;
        {   // 48 rows x 8 f4 = 384 items
            int idx = t;
            if (idx < RWB * 8) {
                int rr = idx >> 3, q4 = idx & 7;
                int fi = rr >> 1, o = rr & 1;
                int f = f0 + fi;
                if (f < Fn) {
                    size_t s = (size_t)(o * Fn + f) * Dn + d0 + 4 * q4;
                    f4v vr = *(const f4v*)(wbr + s);
                    f4v vi = *(const f4v*)(wbi + s);
                    f4v* trow = (f4v*)&tb[rr][0];
                    f4v lo = {vr[0], vi[0], vr[1], vi[1]};
                    f4v hi = {vr[2], vi[2], vr[3], vi[3]};
                    trow[2 * q4]     = lo;
                    trow[2 * q4 + 1] = hi;
                }
            }
        }
        __syncthreads();
        const int items = cnt * FCB;
        for (int base = 0; base < items; base += NT) {
            int it = base + t;
            if (it < items) {
                int m = it / FCB, fi = it - m * FCB;
                int e = bent[off + m];
                int bt = e >> 5, dl = e & 31;
                int f = f0 + fi;
                if (f < Fn) {
                    f2v a = tb[fi * 2][dl];
                    f2v b = tb[fi * 2 + 1][dl];
                    f4v o2 = {a[0], a[1], b[0], b[1]};
                    ((f4v*)out2)[(size_t)bt * Fn + f] = o2;
                }
            }
        }
    }
}

// Fallback (no workspace): direct strided gather, per-block argmin
__global__ __launch_bounds__(256) void main_direct(
    const float* __restrict__ Xr, const float* __restrict__ Xi,
    const float* __restrict__ tdoa, const float2* __restrict__ dirs,
    const float* __restrict__ wcr, const float* __restrict__ wci,
    const float* __restrict__ wdr, const float* __restrict__ wdi,
    const float* __restrict__ wbr, const float* __restrict__ wbi,
    float2* __restrict__ out0, float2* __restrict__ out1, float2* __restrict__ out2) {
    const int bt = blockIdx.x;
    const int tid = threadIdx.x;
    __shared__ double sv[256];
    __shared__ int si[256];

    double t0 = DEG2RAD * (double)tdoa[bt * 2 + 0];
    double t1 = DEG2RAD * (double)tdoa[bt * 2 + 1];
    double ct1 = cos(t1);
    double best = 1e300;
    int bidx = 0;
    for (int d = tid; d < Dn; d += 256) {
        float2 dr = dirs[d];
        double s1 = sin(0.5 * (t1 - (double)dr.y));
        double s2 = sin(0.5 * (t0 - (double)dr.x));
        double a = s1 * s1 + ct1 * cos((double)dr.y) * (s2 * s2);
        if (a < best) { best = a; bidx = d; }
    }
    sv[tid] = best; si[tid] = bidx;
    __syncthreads();
    for (int s = 128; s > 0; s >>= 1) {
        if (tid < s) {
            double v = sv[tid + s]; int j = si[tid + s];
            if (v < sv[tid] || (v == sv[tid] && j < si[tid])) { sv[tid] = v; si[tid] = j; }
        }
        __syncthreads();
    }
    const int dsel = si[0];
    const size_t base = (size_t)bt * Fn * Cn;

    for (int f = tid; f < Fn; f += 256) {
        const int fc = f * Cn;
        float accr = 0.f, acci = 0.f;
        #pragma unroll
        for (int c = 0; c < Cn; ++c) {
            float xr = Xr[base + fc + c], xi = Xi[base + fc + c];
            size_t wo = (size_t)(c * Fn + f) * Dn + dsel;
            float a_ = wdr[wo], b_ = wdi[wo];
            out0[base + fc + c] = make_float2(a_ * xr - b_ * xi, a_ * xi + b_ * xr);
            float p = wcr[wo], q = wci[wo];
            accr += p * xr - q * xi;
            acci += p * xi + q * xr;
        }
        out1[(size_t)bt * Fn + f] = make_float2(accr, acci);
        #pragma unroll
        for (int o = 0; o < On; ++o) {
            size_t wo = (size_t)(o * Fn + f) * Dn + dsel;
            out2[((size_t)bt * Fn + f) * On + o] = make_float2(wbr[wo], wbi[wo]);
        }
    }
}

extern "C" void kernel_launch(void* const* d_in, const int* in_sizes, int n_in,
                              void* d_out, int out_size, void* d_ws, size_t ws_size,
                              hipStream_t stream) {
    const float* Xr   = (const float*)d_in[0];
    const float* Xi   = (const float*)d_in[1];
    const float* tdoa = (const float*)d_in[2];
    const float2* dirs = (const float2*)d_in[3];
    const float* wcr = (const float*)d_in[4];
    const float* wci = (const float*)d_in[5];
    const float* wdr = (const float*)d_in[6];
    const float* wdi = (const float*)d_in[7];
    const float* wbr = (const float*)d_in[8];
    const float* wbi = (const float*)d_in[9];

    float* out = (float*)d_out;

    if (ws_size >= WS_NEEDED) {
        char* ws = (char*)d_ws;
        double* tab   = (double*)ws;
        double* bttab = (double*)(ws + TAB_BYTES);
        int* ind  = (int*)(ws + TAB_BYTES + BTT_PAD);
        int* boff = (int*)(ws + TAB_BYTES + BTT_PAD + IND_BYTES);
        int* bent = (int*)(ws + TAB_BYTES + BTT_PAD + IND_BYTES + BOFF_BYTES);

        build_tables<<<(Dn + BTn + 255) / 256, 256, 0, stream>>>(dirs, tdoa, tab, bttab);
        argmin_lds<<<BTn / 16, 256, 0, stream>>>(bttab, tab, ind);
        bucket_bts<<<1, 256, 0, stream>>>(ind, boff, bent);
        fuse_all<<<NCH * YTOT, NT, 0, stream>>>(Xr, Xi, boff, bent,
                                                wcr, wci, wdr, wdi, wbr, wbi,
                                                out, out + OUT0_F, out + OUT0_F + OUT1_F);
    } else {
        main_direct<<<BTn, 256, 0, stream>>>(Xr, Xi, tdoa, dirs,
                                             wcr, wci, wdr, wdi, wbr, wbi,
                                             (float2*)out,
                                             (float2*)(out + OUT0_F),
                                             (float2*)(out + OUT0_F + OUT1_F));
    }
}